// Round 8
// baseline (41.456 us; speedup 1.0000x reference)
//
#include <hip/hip_runtime.h>
#include <math.h>

#define NS 96
#define NSEG 95
#define LPR 16     // lanes per ray
#define SPL 6      // segments per lane (16*6 = 96 slots, slot 95 fake)
#define RPB 16     // rays per block (256 threads / 16 lanes)

#define CSTR 73    // color LDS row stride in float4 (72 data + 1 pad)
#define DSTR 25    // dep/den LDS row stride in float4 (24 data + 1 pad)

__device__ __forceinline__ float fexp2(float x) { return __builtin_amdgcn_exp2f(x); }
__device__ __forceinline__ float flog2(float x) { return __builtin_amdgcn_logf(x); }

// ---------------------------------------------------------------------------
// Global min/max of depths. Sorted along S: min in samples 0..3, max in
// samples 92..95. Accumulators zero-init (hipMemsetAsync); min uses
// complement encoding (depths > 0 so uint order = float order).
// ---------------------------------------------------------------------------
__global__ __launch_bounds__(256) void minmax_kernel(
    const float4* __restrict__ dep4, unsigned* mm, int n_rays)
{
    __shared__ float slo[4], shi[4];
    const int stride = gridDim.x * blockDim.x;
    float lo = __int_as_float(0x7F7FFFFF), hi = 0.0f;
    for (int ray = blockIdx.x * blockDim.x + threadIdx.x; ray < n_rays; ray += stride) {
        float4 a = dep4[(size_t)ray * 24];        // samples 0..3
        float4 b = dep4[(size_t)ray * 24 + 23];   // samples 92..95
        lo = fminf(lo, fminf(fminf(a.x, a.y), fminf(a.z, a.w)));
        hi = fmaxf(hi, fmaxf(fmaxf(b.x, b.y), fmaxf(b.z, b.w)));
    }
#pragma unroll
    for (int off = 32; off; off >>= 1) {
        lo = fminf(lo, __shfl_xor(lo, off));
        hi = fmaxf(hi, __shfl_xor(hi, off));
    }
    const int wv = threadIdx.x >> 6;
    if ((threadIdx.x & 63) == 0) { slo[wv] = lo; shi[wv] = hi; }
    __syncthreads();
    if (threadIdx.x == 0) {
        lo = fminf(fminf(slo[0], slo[1]), fminf(slo[2], slo[3]));
        hi = fmaxf(fmaxf(shi[0], shi[1]), fmaxf(shi[2], shi[3]));
        atomicMax(&mm[0], ~__float_as_uint(lo));   // complement-encoded min
        atomicMax(&mm[1], __float_as_uint(hi));
    }
}

// ---------------------------------------------------------------------------
// 16 lanes/ray, 6 segments/lane. All three inputs staged to LDS with fully
// coalesced float4 loads (1 KB per wave-instruction), one barrier, then the
// proven per-lane float2 consumption runs against LDS (strides 18*sub /
// 6*sub dwords -> all 32 banks once per 16-lane group, inherent 2-way only).
// ---------------------------------------------------------------------------
__global__ __launch_bounds__(256, 5) void raymarch_kernel(
    const float4* __restrict__ col4,
    const float4* __restrict__ den4,
    const float4* __restrict__ dep4,
    const unsigned* __restrict__ mm,
    float* __restrict__ out_rgb,
    float* __restrict__ out_depth,
    float* __restrict__ out_w,
    int n_rays)
{
    __shared__ float4 scol[RPB * CSTR];   // 18688 B
    __shared__ float4 sdep[RPB * DSTR];   //  6400 B
    __shared__ float4 sden[RPB * DSTR];   //  6400 B   total 31488 B

    const int tid  = threadIdx.x;
    const int base = blockIdx.x * RPB;
    const int vr   = min(base + RPB, n_rays) - base;   // valid rays in tile

    // ---- coalesced staging -------------------------------------------------
    {
        const float4* gc = col4 + (size_t)base * 72;
        const int nc = vr * 72;
#pragma unroll
        for (int q = 0; q < 5; ++q) {
            int f = tid + 256 * q;                 // 0..1279 (need 1152)
            if (f < nc) {
                int r = f / 72;
                scol[r * CSTR + (f - 72 * r)] = gc[f];
            }
        }
        const float4* gd = dep4 + (size_t)base * 24;
        const float4* gn = den4 + (size_t)base * 24;
        const int nd4 = vr * 24;
#pragma unroll
        for (int q = 0; q < 2; ++q) {
            int f = tid + 256 * q;                 // 0..511 (need 384)
            if (f < nd4) {
                int r = f / 24, w = f - 24 * r;
                sdep[r * DSTR + w] = gd[f];
                sden[r * DSTR + w] = gn[f];
            }
        }
    }
    __syncthreads();

    const int lane = tid & 63;
    const int sub  = lane & 15;                    // lane within ray (0..15)
    const int rloc = (tid >> 6) * 4 + (lane >> 4); // ray within block (0..15)
    const int ray  = base + rloc;
    const bool safe = (ray < n_rays);

    const int s0 = sub * SPL;                      // first sample (0,6,..,90)
    const bool lastl = (sub == LPR - 1);

    const float* ldep = (const float*)&sdep[rloc * DSTR] + s0;
    const float* lden = (const float*)&sden[rloc * DSTR] + s0;
    const float* lcol = (const float*)&scol[rloc * CSTR] + 3 * s0;

    // ---- depths / densities: 3 float2 + 1 clamped scalar each -------------
    float d[7], nd[7];
    {
        float2 v;
        v = *(const float2*)(ldep + 0); d[0] = v.x; d[1] = v.y;
        v = *(const float2*)(ldep + 2); d[2] = v.x; d[3] = v.y;
        v = *(const float2*)(ldep + 4); d[4] = v.x; d[5] = v.y;
        d[6] = ldep[lastl ? 5 : 6];    // lastl: d[6]=d[5] -> delta=0 -> w=0
        v = *(const float2*)(lden + 0); nd[0] = v.x; nd[1] = v.y;
        v = *(const float2*)(lden + 2); nd[2] = v.x; nd[3] = v.y;
        v = *(const float2*)(lden + 4); nd[4] = v.x; nd[5] = v.y;
        nd[6] = lden[lastl ? 5 : 6];
    }

    // ---- colors: 21 floats (9 f2 + 1 clamped f2 + 1 clamped scalar) --------
    float c[21];
#pragma unroll
    for (int q = 0; q < 9; ++q) {
        float2 v = *(const float2*)(lcol + 2 * q);
        c[2 * q] = v.x; c[2 * q + 1] = v.y;
    }
    {
        float2 v = *(const float2*)(lcol + (lastl ? 16 : 18));
        c[18] = v.x; c[19] = v.y;          // lastl: dup of c[16..17], w=0 kills
        c[20] = lcol[lastl ? 17 : 20];
    }

    // ---- e_j = exp(-softplus(mid-1)*delta), native exp2/log2 ---------------
    const float LOG2E = 1.4426950408889634f;
    float e[SPL];
#pragma unroll
    for (int j = 0; j < SPL; ++j) {
        float delta = d[j + 1] - d[j];
        float x = (nd[j] + nd[j + 1]) * 0.5f - 1.0f;
        float sp2 = fmaxf(x, 0.f) * LOG2E + flog2(1.0f + fexp2(-fabsf(x) * LOG2E));
        e[j] = fexp2(-delta * sp2);
    }

    // ---- local product + width-16 inclusive scan -> exclusive T ------------
    float P = 1.0f;
#pragma unroll
    for (int j = 0; j < SPL; ++j) P *= (e[j] + 1e-10f);
    float inc = P;
#pragma unroll
    for (int off = 1; off < LPR; off <<= 1) {
        float t = __shfl_up(inc, off, LPR);
        if (sub >= off) inc *= t;
    }
    float Tex = __shfl_up(inc, 1, LPR);
    if (sub == 0) Tex = 1.0f;

    // ---- weights, composites ----------------------------------------------
    float w[SPL];
    float sw = 0.f, sd = 0.f;
    {
        float T = Tex;
#pragma unroll
        for (int j = 0; j < SPL; ++j) {
            w[j] = (1.0f - e[j]) * T;
            T *= (e[j] + 1e-10f);
            sw += w[j];
            sd += w[j] * (d[j] + d[j + 1]);   // x0.5 folded into epilogue
        }
    }

    // ---- weight stores: 3x float2 (wg is 8B-aligned: s0*4 = 24B*sub) ------
    if (safe) {
        float* wg = out_w + (size_t)ray * NSEG + s0;
        *(float2*)(wg + 0) = make_float2(w[0], w[1]);
        *(float2*)(wg + 2) = make_float2(w[2], w[3]);
        if (!lastl) {
            *(float2*)(wg + 4) = make_float2(w[4], w[5]);
        } else {
            wg[4] = w[4];                  // slot 95 doesn't exist
        }
    }

    // ---- rgb partials ------------------------------------------------------
    float sr = 0.f, sg = 0.f, sb = 0.f;
#pragma unroll
    for (int j = 0; j < SPL; ++j) {
        sr += w[j] * (c[3 * j + 0] + c[3 * j + 3]);
        sg += w[j] * (c[3 * j + 1] + c[3 * j + 4]);
        sb += w[j] * (c[3 * j + 2] + c[3 * j + 5]);
    }

    // ---- width-16 butterflies for the 5 composites -------------------------
#pragma unroll
    for (int off = 1; off < LPR; off <<= 1) {
        sw += __shfl_xor(sw, off, LPR);
        sd += __shfl_xor(sd, off, LPR);
        sr += __shfl_xor(sr, off, LPR);
        sg += __shfl_xor(sg, off, LPR);
        sb += __shfl_xor(sb, off, LPR);
    }

    if (sub == 0 && safe) {
        float cd = (0.5f * sd) / sw;
        if (isnan(cd)) cd = __int_as_float(0x7F800000);
        float gmin = __uint_as_float(~mm[0]);   // decode complement min
        float gmax = __uint_as_float(mm[1]);
        cd = fminf(fmaxf(cd, gmin), gmax);
        out_depth[ray] = cd;
        out_rgb[(size_t)ray * 3 + 0] = sr - 1.0f;   // (0.5*sr)*2 - 1
        out_rgb[(size_t)ray * 3 + 1] = sg - 1.0f;
        out_rgb[(size_t)ray * 3 + 2] = sb - 1.0f;
    }
}

// ---------------------------------------------------------------------------
extern "C" void kernel_launch(void* const* d_in, const int* in_sizes, int n_in,
                              void* d_out, int out_size, void* d_ws, size_t ws_size,
                              hipStream_t stream) {
    const float* colors    = (const float*)d_in[0];
    const float* densities = (const float*)d_in[1];
    const float* depths    = (const float*)d_in[2];

    const int n_rays = in_sizes[1] / NS;

    float* out       = (float*)d_out;
    float* out_rgb   = out;
    float* out_depth = out + (size_t)n_rays * 3;
    float* out_w     = out + (size_t)n_rays * 4;

    unsigned* mm = (unsigned*)d_ws;

    hipMemsetAsync(mm, 0, 2 * sizeof(unsigned), stream);
    hipLaunchKernelGGL(minmax_kernel, dim3(128), dim3(256), 0, stream,
                       (const float4*)depths, mm, n_rays);
    hipLaunchKernelGGL(raymarch_kernel,
                       dim3((n_rays + RPB - 1) / RPB), dim3(256), 0, stream,
                       (const float4*)colors, (const float4*)densities,
                       (const float4*)depths, mm,
                       out_rgb, out_depth, out_w, n_rays);
}

// Round 9
// 40.329 us; speedup vs baseline: 1.0280x; 1.0280x over previous
//
#include <hip/hip_runtime.h>
#include <math.h>

#define NS 96
#define NSEG 95
#define LPR 16     // lanes per ray (phase A)
#define SPL 6      // segments per lane (16*6 = 96 slots, slot 95 fake)
#define RPB 16     // rays per block
#define USTR 97    // LDS u row stride (odd -> spread banks)

__device__ __forceinline__ float fexp2(float x) { return __builtin_amdgcn_exp2f(x); }
__device__ __forceinline__ float flog2(float x) { return __builtin_amdgcn_logf(x); }

// ---------------------------------------------------------------------------
// Global min/max of depths (sorted along S: min in samples 0..3, max in
// 92..95). Zero-init accumulators; min is complement-encoded (depths > 0).
// ---------------------------------------------------------------------------
__global__ __launch_bounds__(256) void minmax_kernel(
    const float4* __restrict__ dep4, unsigned* mm, int n_rays)
{
    __shared__ float slo[4], shi[4];
    const int stride = gridDim.x * blockDim.x;
    float lo = __int_as_float(0x7F7FFFFF), hi = 0.0f;
    for (int ray = blockIdx.x * blockDim.x + threadIdx.x; ray < n_rays; ray += stride) {
        float4 a = dep4[(size_t)ray * 24];        // samples 0..3
        float4 b = dep4[(size_t)ray * 24 + 23];   // samples 92..95
        lo = fminf(lo, fminf(fminf(a.x, a.y), fminf(a.z, a.w)));
        hi = fmaxf(hi, fmaxf(fmaxf(b.x, b.y), fmaxf(b.z, b.w)));
    }
#pragma unroll
    for (int off = 32; off; off >>= 1) {
        lo = fminf(lo, __shfl_xor(lo, off));
        hi = fmaxf(hi, __shfl_xor(hi, off));
    }
    const int wv = threadIdx.x >> 6;
    if ((threadIdx.x & 63) == 0) { slo[wv] = lo; shi[wv] = hi; }
    __syncthreads();
    if (threadIdx.x == 0) {
        lo = fminf(fminf(slo[0], slo[1]), fminf(slo[2], slo[3]));
        hi = fmaxf(fmaxf(shi[0], shi[1]), fmaxf(shi[2], shi[3]));
        atomicMax(&mm[0], ~__float_as_uint(lo));   // complement-encoded min
        atomicMax(&mm[1], __float_as_uint(hi));
    }
}

// ---------------------------------------------------------------------------
// Phase A (R6 structure, colors removed): 16 lanes/ray, direct float2 loads
// of dep/den, weights + scan + depth composite; u_s = 0.5*(w_{s-1}+w_s)
// into 6.2 KB LDS. One barrier. Phase B: colors loaded flat-coalesced
// (float4 f = j+16k within ray), multiplied by u from LDS with
// channel-rotation selects, width-16 butterfly, rgb store.
// ---------------------------------------------------------------------------
__global__ __launch_bounds__(256, 5) void raymarch_kernel(
    const float4* __restrict__ col4,
    const float* __restrict__ densities,
    const float* __restrict__ depths,
    const unsigned* __restrict__ mm,
    float* __restrict__ out_rgb,
    float* __restrict__ out_depth,
    float* __restrict__ out_w,
    int n_rays)
{
    __shared__ float su[RPB * USTR];   // 6208 B

    const int tid  = threadIdx.x;
    const int base = blockIdx.x * RPB;
    const int j16  = tid & 15;         // lane within 16-group == sub
    const int rloc = tid >> 4;         // ray within block (0..15)
    const int ray  = base + rloc;
    const int rc   = min(ray, n_rays - 1);
    const bool safe = (ray < n_rays);

    const int sub  = j16;
    const int s0   = sub * SPL;
    const bool lastl = (sub == LPR - 1);

    const float* dep = depths    + (size_t)rc * NS + s0;
    const float* den = densities + (size_t)rc * NS + s0;

    // ---- depths / densities: 3 float2 + 1 clamped scalar each -------------
    float d[7], nd[7];
    {
        float2 v;
        v = *(const float2*)(dep + 0); d[0] = v.x; d[1] = v.y;
        v = *(const float2*)(dep + 2); d[2] = v.x; d[3] = v.y;
        v = *(const float2*)(dep + 4); d[4] = v.x; d[5] = v.y;
        d[6] = dep[lastl ? 5 : 6];     // lastl: d[6]=d[5] -> delta=0 -> w=0
        v = *(const float2*)(den + 0); nd[0] = v.x; nd[1] = v.y;
        v = *(const float2*)(den + 2); nd[2] = v.x; nd[3] = v.y;
        v = *(const float2*)(den + 4); nd[4] = v.x; nd[5] = v.y;
        nd[6] = den[lastl ? 5 : 6];
    }

    // ---- e_j = exp(-softplus(mid-1)*delta), native exp2/log2 ---------------
    const float LOG2E = 1.4426950408889634f;
    float e[SPL];
#pragma unroll
    for (int j = 0; j < SPL; ++j) {
        float delta = d[j + 1] - d[j];
        float x = (nd[j] + nd[j + 1]) * 0.5f - 1.0f;
        float sp2 = fmaxf(x, 0.f) * LOG2E + flog2(1.0f + fexp2(-fabsf(x) * LOG2E));
        e[j] = fexp2(-delta * sp2);
    }

    // ---- local product + width-16 inclusive scan -> exclusive T ------------
    float P = 1.0f;
#pragma unroll
    for (int j = 0; j < SPL; ++j) P *= (e[j] + 1e-10f);
    float inc = P;
#pragma unroll
    for (int off = 1; off < LPR; off <<= 1) {
        float t = __shfl_up(inc, off, LPR);
        if (sub >= off) inc *= t;
    }
    float Tex = __shfl_up(inc, 1, LPR);
    if (sub == 0) Tex = 1.0f;

    // ---- weights + sw/sd composites ----------------------------------------
    float w[SPL];
    float sw = 0.f, sd = 0.f;
    {
        float T = Tex;
#pragma unroll
        for (int j = 0; j < SPL; ++j) {
            w[j] = (1.0f - e[j]) * T;
            T *= (e[j] + 1e-10f);
            sw += w[j];
            sd += w[j] * (d[j] + d[j + 1]);   // x0.5 folded into epilogue
        }
    }

    // ---- u coefficients into LDS: u_s = 0.5*(w_{s-1}+w_s) ------------------
    float wprev = __shfl_up(w[SPL - 1], 1, LPR);
    if (sub == 0) wprev = 0.0f;            // w_{-1} = 0
    {
        float* ur = su + rloc * USTR + s0;
        ur[0] = 0.5f * (wprev + w[0]);
        ur[1] = 0.5f * (w[0] + w[1]);
        ur[2] = 0.5f * (w[1] + w[2]);
        ur[3] = 0.5f * (w[2] + w[3]);
        ur[4] = 0.5f * (w[3] + w[4]);
        ur[5] = 0.5f * (w[4] + w[5]);      // lane15: u95 = 0.5*w94 (w[5]=0)
    }

    // ---- weight stores: 3x float2 ------------------------------------------
    if (safe) {
        float* wg = out_w + (size_t)ray * NSEG + s0;
        *(float2*)(wg + 0) = make_float2(w[0], w[1]);
        *(float2*)(wg + 2) = make_float2(w[2], w[3]);
        if (!lastl) {
            *(float2*)(wg + 4) = make_float2(w[4], w[5]);
        } else {
            wg[4] = w[4];                  // slot 95 doesn't exist
        }
    }

    // ---- width-16 butterflies for sw, sd + depth epilogue ------------------
#pragma unroll
    for (int off = 1; off < LPR; off <<= 1) {
        sw += __shfl_xor(sw, off, LPR);
        sd += __shfl_xor(sd, off, LPR);
    }
    if (sub == 0 && safe) {
        float cd = (0.5f * sd) / sw;
        if (isnan(cd)) cd = __int_as_float(0x7F800000);
        float gmin = __uint_as_float(~mm[0]);
        float gmax = __uint_as_float(mm[1]);
        cd = fminf(fmaxf(cd, gmin), gmax);
        out_depth[ray] = cd;
    }

    __syncthreads();

    // ======================= Phase B: coalesced colors ======================
    // thread (rloc, j16) handles float4 f = j16 + 16k of ray rloc (f < 72).
    // float4 f covers float positions 4f..4f+3 = samples sA, sA+1 where
    // sA = 4f/3, r0 = f mod 3; element m: sample sA+(r0+m>=3),
    // channel (r0+m) mod 3.
    {
        const float4* gcol = col4 + (size_t)base * 72 + (size_t)rloc * 72;
        const float* urow = su + rloc * USTR;

        int sA = (4 * j16) / 3;
        int r0 = 4 * j16 - 3 * sA;         // = j16 % 3
        float pr = 0.f, pg = 0.f, pb = 0.f;
#pragma unroll
        for (int k = 0; k < 5; ++k) {
            const int f = j16 + 16 * k;
            if (f < 72 && safe) {
                float4 v = gcol[f];
                float uA = urow[sA], uB = urow[sA + 1];
                float vs0 = v.x, vs1 = v.y, vs2 = v.z, vs3 = v.w;
#pragma unroll
                for (int m = 0; m < 4; ++m) {
                    float vm = (m == 0) ? vs0 : (m == 1) ? vs1 : (m == 2) ? vs2 : vs3;
                    int q = r0 + m;                 // 0..5
                    float uu = (q >= 3) ? uB : uA;
                    int ch = (q >= 3) ? q - 3 : q;  // channel
                    float val = vm * uu;
                    pr += (ch == 0) ? val : 0.f;
                    pg += (ch == 1) ? val : 0.f;
                    pb += (ch == 2) ? val : 0.f;
                }
            }
            // advance: 4(f+16) = 3(sA+21) + r0+1  (wrap at r0==2 -> +22)
            sA += (r0 == 2) ? 22 : 21;
            r0 = (r0 == 2) ? 0 : r0 + 1;
        }

        // width-16 butterfly (group == one ray)
#pragma unroll
        for (int off = 1; off < LPR; off <<= 1) {
            pr += __shfl_xor(pr, off, LPR);
            pg += __shfl_xor(pg, off, LPR);
            pb += __shfl_xor(pb, off, LPR);
        }
        if (j16 == 0 && safe) {
            out_rgb[(size_t)ray * 3 + 0] = pr * 2.0f - 1.0f;
            out_rgb[(size_t)ray * 3 + 1] = pg * 2.0f - 1.0f;
            out_rgb[(size_t)ray * 3 + 2] = pb * 2.0f - 1.0f;
        }
    }
}

// ---------------------------------------------------------------------------
extern "C" void kernel_launch(void* const* d_in, const int* in_sizes, int n_in,
                              void* d_out, int out_size, void* d_ws, size_t ws_size,
                              hipStream_t stream) {
    const float* colors    = (const float*)d_in[0];
    const float* densities = (const float*)d_in[1];
    const float* depths    = (const float*)d_in[2];

    const int n_rays = in_sizes[1] / NS;

    float* out       = (float*)d_out;
    float* out_rgb   = out;
    float* out_depth = out + (size_t)n_rays * 3;
    float* out_w     = out + (size_t)n_rays * 4;

    unsigned* mm = (unsigned*)d_ws;

    hipMemsetAsync(mm, 0, 2 * sizeof(unsigned), stream);
    hipLaunchKernelGGL(minmax_kernel, dim3(128), dim3(256), 0, stream,
                       (const float4*)depths, mm, n_rays);
    hipLaunchKernelGGL(raymarch_kernel,
                       dim3((n_rays + RPB - 1) / RPB), dim3(256), 0, stream,
                       (const float4*)colors, densities, depths, mm,
                       out_rgb, out_depth, out_w, n_rays);
}

// Round 10
// 37.769 us; speedup vs baseline: 1.0976x; 1.0678x over previous
//
#include <hip/hip_runtime.h>
#include <math.h>

#define NS 96
#define NSEG 95
#define LPR 16     // lanes per ray
#define SPL 6      // segments per lane (16*6 = 96 slots, slot 95 fake)
#define RPB 16     // rays per block (256 threads / 16 lanes)

__device__ __forceinline__ float fexp2(float x) { return __builtin_amdgcn_exp2f(x); }
__device__ __forceinline__ float flog2(float x) { return __builtin_amdgcn_logf(x); }

// ---------------------------------------------------------------------------
// Global min/max of depths. Sorted along S, so min lives in samples 0..3 and
// max in samples 92..95 of each ray. Accumulators zero-init (memset); min is
// complement-encoded (depths > 0 so uint order = float order).
// ---------------------------------------------------------------------------
__global__ __launch_bounds__(256) void minmax_kernel(
    const float4* __restrict__ dep4, unsigned* mm, int n_rays)
{
    __shared__ float slo[4], shi[4];
    const int stride = gridDim.x * blockDim.x;
    float lo = __int_as_float(0x7F7FFFFF), hi = 0.0f;
    for (int ray = blockIdx.x * blockDim.x + threadIdx.x; ray < n_rays; ray += stride) {
        float4 a = dep4[(size_t)ray * 24];        // samples 0..3
        float4 b = dep4[(size_t)ray * 24 + 23];   // samples 92..95
        lo = fminf(lo, fminf(fminf(a.x, a.y), fminf(a.z, a.w)));
        hi = fmaxf(hi, fmaxf(fmaxf(b.x, b.y), fmaxf(b.z, b.w)));
    }
#pragma unroll
    for (int off = 32; off; off >>= 1) {
        lo = fminf(lo, __shfl_xor(lo, off));
        hi = fmaxf(hi, __shfl_xor(hi, off));
    }
    const int wv = threadIdx.x >> 6;
    if ((threadIdx.x & 63) == 0) { slo[wv] = lo; shi[wv] = hi; }
    __syncthreads();
    if (threadIdx.x == 0) {
        lo = fminf(fminf(slo[0], slo[1]), fminf(slo[2], slo[3]));
        hi = fmaxf(fmaxf(shi[0], shi[1]), fmaxf(shi[2], shi[3]));
        atomicMax(&mm[0], ~__float_as_uint(lo));   // complement-encoded min
        atomicMax(&mm[1], __float_as_uint(hi));
    }
}

// ---------------------------------------------------------------------------
// 16 lanes per ray, 6 segments per lane. No LDS, no barriers. All 19 global
// loads are forced to issue as ONE cluster via sched_group_barrier(VMEM_READ)
// before any math, so the full load set is in flight concurrently (MLP),
// instead of the allocator's 2-at-a-time load-sinking (R9: VGPR=16).
// ---------------------------------------------------------------------------
__global__ __launch_bounds__(256, 4) void raymarch_kernel(
    const float* __restrict__ colors,
    const float* __restrict__ densities,
    const float* __restrict__ depths,
    const unsigned* __restrict__ mm,
    float* __restrict__ out_rgb,
    float* __restrict__ out_depth,
    float* __restrict__ out_w,
    int n_rays)
{
    const int tid  = threadIdx.x;
    const int lane = tid & 63;
    const int sub  = lane & 15;                    // lane within ray (0..15)
    const int rloc = (tid >> 6) * 4 + (lane >> 4); // ray within block (0..15)
    const int ray  = blockIdx.x * RPB + rloc;
    if (ray >= n_rays) return;

    const int s0 = sub * SPL;                      // first sample (0,6,..,90)
    const bool lastl = (sub == LPR - 1);

    const float* dep = depths    + (size_t)ray * NS + s0;
    const float* den = densities + (size_t)ray * NS + s0;
    const float* col = colors    + (size_t)ray * NS * 3 + 3 * s0;

    // ---- issue ALL loads up front ------------------------------------------
    float2 dv0 = *(const float2*)(dep + 0);
    float2 dv1 = *(const float2*)(dep + 2);
    float2 dv2 = *(const float2*)(dep + 4);
    float  d6  = dep[lastl ? 5 : 6];   // lastl: d[6]=d[5] -> delta=0 -> w=0
    float2 nv0 = *(const float2*)(den + 0);
    float2 nv1 = *(const float2*)(den + 2);
    float2 nv2 = *(const float2*)(den + 4);
    float  n6  = den[lastl ? 5 : 6];

    float2 cv[9];
#pragma unroll
    for (int q = 0; q < 9; ++q) cv[q] = *(const float2*)(col + 2 * q);
    float2 cvt = *(const float2*)(col + (lastl ? 16 : 18));
    float  c20 = col[lastl ? 17 : 20];

    // force the scheduler to emit all 19 VMEM reads as one cluster here
    __builtin_amdgcn_sched_group_barrier(0x20 /*VMEM_READ*/, 19, 0);

    // ---- unpack ------------------------------------------------------------
    float d[7], nd[7];
    d[0] = dv0.x; d[1] = dv0.y; d[2] = dv1.x; d[3] = dv1.y;
    d[4] = dv2.x; d[5] = dv2.y; d[6] = d6;
    nd[0] = nv0.x; nd[1] = nv0.y; nd[2] = nv1.x; nd[3] = nv1.y;
    nd[4] = nv2.x; nd[5] = nv2.y; nd[6] = n6;

    float c[21];
#pragma unroll
    for (int q = 0; q < 9; ++q) { c[2 * q] = cv[q].x; c[2 * q + 1] = cv[q].y; }
    c[18] = cvt.x; c[19] = cvt.y;      // lastl: dup of c[16..17], w=0 kills
    c[20] = c20;

    // ---- e_j = exp(-softplus(mid-1)*delta), native exp2/log2 ---------------
    const float LOG2E = 1.4426950408889634f;
    float e[SPL];
#pragma unroll
    for (int j = 0; j < SPL; ++j) {
        float delta = d[j + 1] - d[j];
        float x = (nd[j] + nd[j + 1]) * 0.5f - 1.0f;
        float sp2 = fmaxf(x, 0.f) * LOG2E + flog2(1.0f + fexp2(-fabsf(x) * LOG2E));
        e[j] = fexp2(-delta * sp2);
    }

    // ---- local product + width-16 inclusive scan -> exclusive T ------------
    float P = 1.0f;
#pragma unroll
    for (int j = 0; j < SPL; ++j) P *= (e[j] + 1e-10f);
    float inc = P;
#pragma unroll
    for (int off = 1; off < LPR; off <<= 1) {
        float t = __shfl_up(inc, off, LPR);
        if (sub >= off) inc *= t;
    }
    float Tex = __shfl_up(inc, 1, LPR);
    if (sub == 0) Tex = 1.0f;

    // ---- weights, composites ----------------------------------------------
    float w[SPL];
    float sw = 0.f, sd = 0.f;
    {
        float T = Tex;
#pragma unroll
        for (int j = 0; j < SPL; ++j) {
            w[j] = (1.0f - e[j]) * T;
            T *= (e[j] + 1e-10f);
            sw += w[j];
            sd += w[j] * (d[j] + d[j + 1]);   // x0.5 folded into epilogue
        }
    }

    // ---- weight stores: 3x float2 (wg is 8B-aligned: s0*4 = 24B*sub) ------
    float* wg = out_w + (size_t)ray * NSEG + s0;
    *(float2*)(wg + 0) = make_float2(w[0], w[1]);
    *(float2*)(wg + 2) = make_float2(w[2], w[3]);
    if (!lastl) {
        *(float2*)(wg + 4) = make_float2(w[4], w[5]);
    } else {
        wg[4] = w[4];                      // slot 95 doesn't exist
    }

    // ---- rgb partials ------------------------------------------------------
    float sr = 0.f, sg = 0.f, sb = 0.f;
#pragma unroll
    for (int j = 0; j < SPL; ++j) {
        sr += w[j] * (c[3 * j + 0] + c[3 * j + 3]);
        sg += w[j] * (c[3 * j + 1] + c[3 * j + 4]);
        sb += w[j] * (c[3 * j + 2] + c[3 * j + 5]);
    }

    // ---- width-16 butterflies for the 5 composites -------------------------
#pragma unroll
    for (int off = 1; off < LPR; off <<= 1) {
        sw += __shfl_xor(sw, off, LPR);
        sd += __shfl_xor(sd, off, LPR);
        sr += __shfl_xor(sr, off, LPR);
        sg += __shfl_xor(sg, off, LPR);
        sb += __shfl_xor(sb, off, LPR);
    }

    if (sub == 0) {
        float cd = (0.5f * sd) / sw;
        if (isnan(cd)) cd = __int_as_float(0x7F800000);
        float gmin = __uint_as_float(~mm[0]);   // decode complement min
        float gmax = __uint_as_float(mm[1]);
        cd = fminf(fmaxf(cd, gmin), gmax);
        out_depth[ray] = cd;
        out_rgb[(size_t)ray * 3 + 0] = sr - 1.0f;   // (0.5*sr)*2 - 1
        out_rgb[(size_t)ray * 3 + 1] = sg - 1.0f;
        out_rgb[(size_t)ray * 3 + 2] = sb - 1.0f;
    }
}

// ---------------------------------------------------------------------------
extern "C" void kernel_launch(void* const* d_in, const int* in_sizes, int n_in,
                              void* d_out, int out_size, void* d_ws, size_t ws_size,
                              hipStream_t stream) {
    const float* colors    = (const float*)d_in[0];
    const float* densities = (const float*)d_in[1];
    const float* depths    = (const float*)d_in[2];

    const int n_rays = in_sizes[1] / NS;

    float* out       = (float*)d_out;
    float* out_rgb   = out;
    float* out_depth = out + (size_t)n_rays * 3;
    float* out_w     = out + (size_t)n_rays * 4;

    unsigned* mm = (unsigned*)d_ws;

    hipMemsetAsync(mm, 0, 2 * sizeof(unsigned), stream);
    hipLaunchKernelGGL(minmax_kernel, dim3(128), dim3(256), 0, stream,
                       (const float4*)depths, mm, n_rays);
    hipLaunchKernelGGL(raymarch_kernel,
                       dim3((n_rays + RPB - 1) / RPB), dim3(256), 0, stream,
                       colors, densities, depths, mm,
                       out_rgb, out_depth, out_w, n_rays);
}

// Round 12
// 27.970 us; speedup vs baseline: 1.4822x; 1.3504x over previous
//
#include <hip/hip_runtime.h>
#include <math.h>

#define NS 96
#define NSEG 95
#define LPR 16     // lanes per ray
#define SPL 6      // segments per lane (16*6 = 96 slots, slot 95 fake)
#define RPB 16     // rays per block (256 threads / 16 lanes)

__device__ __forceinline__ float fexp2(float x) { return __builtin_amdgcn_exp2f(x); }
__device__ __forceinline__ float flog2(float x) { return __builtin_amdgcn_logf(x); }

// Inline-asm volatile loads: cannot be sunk by the scheduler/allocator; the
// result register stays live from issue to use -> forced memory-level
// parallelism (R10 showed sched_group_barrier is ignored: VGPR=28).
__device__ __forceinline__ float2 gl2(const float* p) {
    float2 r;
    asm volatile("global_load_dwordx2 %0, %1, off" : "=v"(r) : "v"(p));
    return r;
}
__device__ __forceinline__ float gl1(const float* p) {
    float r;
    asm volatile("global_load_dword %0, %1, off" : "=v"(r) : "v"(p));
    return r;
}

// ---------------------------------------------------------------------------
// Single kernel. 16 lanes/ray, 6 segments/lane, no LDS, no barriers.
// Global depth min/max eliminated: cd is a convex combination of this ray's
// depth midpoints, so clamp to [ray_d0, ray_d95] == clamp to global range
// (both are no-ops when sw > 0, which softplus>0 & sorted depths guarantee).
// ---------------------------------------------------------------------------
__global__ __launch_bounds__(256, 4) void raymarch_kernel(
    const float* __restrict__ colors,
    const float* __restrict__ densities,
    const float* __restrict__ depths,
    float* __restrict__ out_rgb,
    float* __restrict__ out_depth,
    float* __restrict__ out_w,
    int n_rays)
{
    const int tid  = threadIdx.x;
    const int lane = tid & 63;
    const int sub  = lane & 15;                    // lane within ray (0..15)
    const int rloc = (tid >> 6) * 4 + (lane >> 4); // ray within block (0..15)
    const int ray  = blockIdx.x * RPB + rloc;
    if (ray >= n_rays) return;

    const int s0 = sub * SPL;                      // first sample (0,6,..,90)
    const bool lastl = (sub == LPR - 1);

    const float* dep = depths    + (size_t)ray * NS + s0;
    const float* den = densities + (size_t)ray * NS + s0;
    const float* col = colors    + (size_t)ray * NS * 3 + 3 * s0;

    // ---- colors: 11 asm-volatile loads issued up front, all in flight ------
    float2 cv[9];
#pragma unroll
    for (int q = 0; q < 9; ++q) cv[q] = gl2(col + 2 * q);
    float2 cvt = gl2(col + (lastl ? 16 : 18));
    float  c20 = gl1(col + (lastl ? 17 : 20));

    // ---- dep/den: plain C loads (consumed first; compiler schedules) -------
    float d[7], nd[7];
    {
        float2 v;
        v = *(const float2*)(dep + 0); d[0] = v.x; d[1] = v.y;
        v = *(const float2*)(dep + 2); d[2] = v.x; d[3] = v.y;
        v = *(const float2*)(dep + 4); d[4] = v.x; d[5] = v.y;
        d[6] = dep[lastl ? 5 : 6];     // lastl: d[6]=d[5] -> delta=0 -> w=0
        v = *(const float2*)(den + 0); nd[0] = v.x; nd[1] = v.y;
        v = *(const float2*)(den + 2); nd[2] = v.x; nd[3] = v.y;
        v = *(const float2*)(den + 4); nd[4] = v.x; nd[5] = v.y;
        nd[6] = den[lastl ? 5 : 6];
    }

    // ---- e_j = exp(-softplus(mid-1)*delta), native exp2/log2 ---------------
    const float LOG2E = 1.4426950408889634f;
    float e[SPL];
#pragma unroll
    for (int j = 0; j < SPL; ++j) {
        float delta = d[j + 1] - d[j];
        float x = (nd[j] + nd[j + 1]) * 0.5f - 1.0f;
        float sp2 = fmaxf(x, 0.f) * LOG2E + flog2(1.0f + fexp2(-fabsf(x) * LOG2E));
        e[j] = fexp2(-delta * sp2);
    }

    // ---- local product + width-16 inclusive scan -> exclusive T ------------
    float P = 1.0f;
#pragma unroll
    for (int j = 0; j < SPL; ++j) P *= (e[j] + 1e-10f);
    float inc = P;
#pragma unroll
    for (int off = 1; off < LPR; off <<= 1) {
        float t = __shfl_up(inc, off, LPR);
        if (sub >= off) inc *= t;
    }
    float Tex = __shfl_up(inc, 1, LPR);
    if (sub == 0) Tex = 1.0f;

    // ---- weights, sw/sd composites -----------------------------------------
    float w[SPL];
    float sw = 0.f, sd = 0.f;
    {
        float T = Tex;
#pragma unroll
        for (int j = 0; j < SPL; ++j) {
            w[j] = (1.0f - e[j]) * T;
            T *= (e[j] + 1e-10f);
            sw += w[j];
            sd += w[j] * (d[j] + d[j + 1]);   // x0.5 folded into epilogue
        }
    }

    // ---- per-ray clamp bounds: shuffles done while ALL lanes active --------
    // (R11 bug: shfl inside the divergent sub==0 branch read an inactive
    //  lane -> 0 -> every depth clamped to 0. Hoist above the branch.)
    float rmax = __shfl(d[6], LPR - 1, LPR);   // lane15's d[6] = sample 95
    float rmin = __shfl(d[0], 0, LPR);         // lane0's d[0] = sample 0

    // ---- drain the color loads; block hoisting of consumers (rule #18) ----
    asm volatile("s_waitcnt vmcnt(0)" ::: "memory");
    __builtin_amdgcn_sched_barrier(0);

    float c[21];
#pragma unroll
    for (int q = 0; q < 9; ++q) { c[2 * q] = cv[q].x; c[2 * q + 1] = cv[q].y; }
    c[18] = cvt.x; c[19] = cvt.y;      // lastl: dup of c[16..17], w=0 kills
    c[20] = c20;

    // ---- rgb partials ------------------------------------------------------
    float sr = 0.f, sg = 0.f, sb = 0.f;
#pragma unroll
    for (int j = 0; j < SPL; ++j) {
        sr += w[j] * (c[3 * j + 0] + c[3 * j + 3]);
        sg += w[j] * (c[3 * j + 1] + c[3 * j + 4]);
        sb += w[j] * (c[3 * j + 2] + c[3 * j + 5]);
    }

    // ---- width-16 butterflies for the 5 composites -------------------------
#pragma unroll
    for (int off = 1; off < LPR; off <<= 1) {
        sw += __shfl_xor(sw, off, LPR);
        sd += __shfl_xor(sd, off, LPR);
        sr += __shfl_xor(sr, off, LPR);
        sg += __shfl_xor(sg, off, LPR);
        sb += __shfl_xor(sb, off, LPR);
    }

    // ---- weight stores: 3x float2 (wg is 8B-aligned: s0*4 = 24B*sub) ------
    float* wg = out_w + (size_t)ray * NSEG + s0;
    *(float2*)(wg + 0) = make_float2(w[0], w[1]);
    *(float2*)(wg + 2) = make_float2(w[2], w[3]);
    if (!lastl) {
        *(float2*)(wg + 4) = make_float2(w[4], w[5]);
    } else {
        wg[4] = w[4];                      // slot 95 doesn't exist
    }

    // ---- epilogue ----------------------------------------------------------
    if (sub == 0) {
        float cd = (0.5f * sd) / sw;
        if (isnan(cd)) cd = __int_as_float(0x7F800000);
        cd = fminf(fmaxf(cd, rmin), rmax);
        out_depth[ray] = cd;
        out_rgb[(size_t)ray * 3 + 0] = sr - 1.0f;   // (0.5*sr)*2 - 1
        out_rgb[(size_t)ray * 3 + 1] = sg - 1.0f;
        out_rgb[(size_t)ray * 3 + 2] = sb - 1.0f;
    }
}

// ---------------------------------------------------------------------------
extern "C" void kernel_launch(void* const* d_in, const int* in_sizes, int n_in,
                              void* d_out, int out_size, void* d_ws, size_t ws_size,
                              hipStream_t stream) {
    const float* colors    = (const float*)d_in[0];
    const float* densities = (const float*)d_in[1];
    const float* depths    = (const float*)d_in[2];

    const int n_rays = in_sizes[1] / NS;

    float* out       = (float*)d_out;
    float* out_rgb   = out;
    float* out_depth = out + (size_t)n_rays * 3;
    float* out_w     = out + (size_t)n_rays * 4;

    hipLaunchKernelGGL(raymarch_kernel,
                       dim3((n_rays + RPB - 1) / RPB), dim3(256), 0, stream,
                       colors, densities, depths,
                       out_rgb, out_depth, out_w, n_rays);
}

// Round 13
// 27.016 us; speedup vs baseline: 1.5345x; 1.0353x over previous
//
#include <hip/hip_runtime.h>
#include <math.h>

#define NS 96
#define NSEG 95
#define LPR 16     // lanes per ray
#define SPL 6      // segments per lane (16*6 = 96 slots, slot 95 fake)
#define RPB 16     // rays per block (256 threads / 16 lanes)

__device__ __forceinline__ float fexp2(float x) { return __builtin_amdgcn_exp2f(x); }
__device__ __forceinline__ float flog2(float x) { return __builtin_amdgcn_logf(x); }

// Direct global->LDS DMA (no VGPR roundtrip, compiler-tracked in vmcnt).
// LDS dst is wave-uniform base + lane*size; our per-lane ptrs satisfy that.
__device__ __forceinline__ void cp16(void* lds, const void* g) {
    __builtin_amdgcn_global_load_lds(
        (const __attribute__((address_space(1))) unsigned int*)g,
        (__attribute__((address_space(3))) unsigned int*)lds, 16, 0, 0);
}
__device__ __forceinline__ void cp4(void* lds, const void* g) {
    __builtin_amdgcn_global_load_lds(
        (const __attribute__((address_space(1))) unsigned int*)g,
        (__attribute__((address_space(3))) unsigned int*)lds, 4, 0, 0);
}

// Inline-asm volatile loads: cannot be sunk -> forced MLP (R12: proven win).
__device__ __forceinline__ float2 gl2(const float* p) {
    float2 r;
    asm volatile("global_load_dwordx2 %0, %1, off" : "=v"(r) : "v"(p));
    return r;
}
__device__ __forceinline__ float gl1(const float* p) {
    float r;
    asm volatile("global_load_dword %0, %1, off" : "=v"(r) : "v"(p));
    return r;
}

// ---------------------------------------------------------------------------
// Single kernel, no barriers. Wave w stages its OWN 4 rays' colors into its
// own LDS segment (6 coalesced LDS-DMA instrs, ~36 lines/wave vs ~420 for the
// per-lane gather), so vmcnt(0) alone orders producer->consumer. dep/den are
// asm-volatile per-lane loads (all in flight concurrently). Per-ray depth
// clamp == global clamp (cd is a convex combination of this ray's midpoints;
// sw > 0 always since softplus > 0 and depths strictly sorted).
// ---------------------------------------------------------------------------
__global__ __launch_bounds__(256, 4) void raymarch_kernel(
    const float* __restrict__ colors,
    const float* __restrict__ densities,
    const float* __restrict__ depths,
    float* __restrict__ out_rgb,
    float* __restrict__ out_depth,
    float* __restrict__ out_w,
    int n_rays)
{
    __shared__ float scol[RPB * 288];   // 18432 B -> 8 blocks/CU

    const int tid  = threadIdx.x;
    const int wv   = tid >> 6;
    const int lane = tid & 63;
    const int sub  = tid & 15;                 // lane within ray (0..15)
    const int rloc = tid >> 4;                 // ray within block (0..15)
    const int base = blockIdx.x * RPB;
    const int ray  = base + rloc;

    // ---- stage this wave's 4 rays of colors (fire-and-forget) --------------
    {
        const int wray = base + wv * 4;
        if (wray + 4 <= n_rays) {
            const float4* gq = (const float4*)colors + (size_t)wray * 72;
            float4* sq = (float4*)scol + wv * 288;
#pragma unroll
            for (int q = 0; q < 4; ++q)                 // 4 x 1KB contiguous
                cp16(sq + 64 * q + lane, gq + 64 * q + lane);
            const float* gdw = colors + (size_t)wray * 288;
            float* sdw = scol + wv * 1152;
            cp4(sdw + 1024 + lane, gdw + 1024 + lane);  // tail 512B
            cp4(sdw + 1088 + lane, gdw + 1088 + lane);
        }
    }

    if (ray >= n_rays) return;

    const int s0 = sub * SPL;                  // first sample (0,6,..,90)
    const bool lastl = (sub == LPR - 1);

    const float* dep = depths    + (size_t)ray * NS + s0;
    const float* den = densities + (size_t)ray * NS + s0;

    // ---- dep/den: 8 asm-volatile loads, all in flight ----------------------
    float2 dv0 = gl2(dep + 0);
    float2 dv1 = gl2(dep + 2);
    float2 dv2 = gl2(dep + 4);
    float  d6  = gl1(dep + (lastl ? 5 : 6));  // lastl: delta=0 -> w=0
    float2 nv0 = gl2(den + 0);
    float2 nv1 = gl2(den + 2);
    float2 nv2 = gl2(den + 4);
    float  n6  = gl1(den + (lastl ? 5 : 6));

    // ---- single drain: dep/den results valid AND colors landed in LDS -----
    asm volatile("s_waitcnt vmcnt(0)" ::: "memory");
    __builtin_amdgcn_sched_barrier(0);

    float d[7], nd[7];
    d[0] = dv0.x; d[1] = dv0.y; d[2] = dv1.x; d[3] = dv1.y;
    d[4] = dv2.x; d[5] = dv2.y; d[6] = d6;
    nd[0] = nv0.x; nd[1] = nv0.y; nd[2] = nv1.x; nd[3] = nv1.y;
    nd[4] = nv2.x; nd[5] = nv2.y; nd[6] = n6;

    // ---- e_j = exp(-softplus(mid-1)*delta), native exp2/log2 ---------------
    const float LOG2E = 1.4426950408889634f;
    float e[SPL];
#pragma unroll
    for (int j = 0; j < SPL; ++j) {
        float delta = d[j + 1] - d[j];
        float x = (nd[j] + nd[j + 1]) * 0.5f - 1.0f;
        float sp2 = fmaxf(x, 0.f) * LOG2E + flog2(1.0f + fexp2(-fabsf(x) * LOG2E));
        e[j] = fexp2(-delta * sp2);
    }

    // ---- local product + width-16 inclusive scan -> exclusive T ------------
    float P = 1.0f;
#pragma unroll
    for (int j = 0; j < SPL; ++j) P *= (e[j] + 1e-10f);
    float inc = P;
#pragma unroll
    for (int off = 1; off < LPR; off <<= 1) {
        float t = __shfl_up(inc, off, LPR);
        if (sub >= off) inc *= t;
    }
    float Tex = __shfl_up(inc, 1, LPR);
    if (sub == 0) Tex = 1.0f;

    // ---- weights, sw/sd composites -----------------------------------------
    float w[SPL];
    float sw = 0.f, sd = 0.f;
    {
        float T = Tex;
#pragma unroll
        for (int j = 0; j < SPL; ++j) {
            w[j] = (1.0f - e[j]) * T;
            T *= (e[j] + 1e-10f);
            sw += w[j];
            sd += w[j] * (d[j] + d[j + 1]);   // x0.5 folded into epilogue
        }
    }

    // ---- per-ray clamp bounds: shuffles while ALL lanes active -------------
    float rmax = __shfl(d[6], LPR - 1, LPR);   // lane15's d[6] = sample 95
    float rmin = __shfl(d[0], 0, LPR);         // lane0's d[0] = sample 0

    // ---- colors from this wave's LDS segment -------------------------------
    const float* lcol = scol + rloc * 288 + 3 * s0;
    float c[21];
#pragma unroll
    for (int q = 0; q < 9; ++q) {
        float2 v = *(const float2*)(lcol + 2 * q);
        c[2 * q] = v.x; c[2 * q + 1] = v.y;
    }
    {
        float2 v = *(const float2*)(lcol + (lastl ? 16 : 18));
        c[18] = v.x; c[19] = v.y;          // lastl: dup of c[16..17], w=0 kills
        c[20] = lcol[lastl ? 17 : 20];
    }

    // ---- rgb partials ------------------------------------------------------
    float sr = 0.f, sg = 0.f, sb = 0.f;
#pragma unroll
    for (int j = 0; j < SPL; ++j) {
        sr += w[j] * (c[3 * j + 0] + c[3 * j + 3]);
        sg += w[j] * (c[3 * j + 1] + c[3 * j + 4]);
        sb += w[j] * (c[3 * j + 2] + c[3 * j + 5]);
    }

    // ---- width-16 butterflies for the 5 composites -------------------------
#pragma unroll
    for (int off = 1; off < LPR; off <<= 1) {
        sw += __shfl_xor(sw, off, LPR);
        sd += __shfl_xor(sd, off, LPR);
        sr += __shfl_xor(sr, off, LPR);
        sg += __shfl_xor(sg, off, LPR);
        sb += __shfl_xor(sb, off, LPR);
    }

    // ---- weight stores: 3x float2 (wg is 8B-aligned: s0*4 = 24B*sub) ------
    float* wg = out_w + (size_t)ray * NSEG + s0;
    *(float2*)(wg + 0) = make_float2(w[0], w[1]);
    *(float2*)(wg + 2) = make_float2(w[2], w[3]);
    if (!lastl) {
        *(float2*)(wg + 4) = make_float2(w[4], w[5]);
    } else {
        wg[4] = w[4];                      // slot 95 doesn't exist
    }

    // ---- epilogue ----------------------------------------------------------
    if (sub == 0) {
        float cd = (0.5f * sd) / sw;
        if (isnan(cd)) cd = __int_as_float(0x7F800000);
        cd = fminf(fmaxf(cd, rmin), rmax);
        out_depth[ray] = cd;
        out_rgb[(size_t)ray * 3 + 0] = sr - 1.0f;   // (0.5*sr)*2 - 1
        out_rgb[(size_t)ray * 3 + 1] = sg - 1.0f;
        out_rgb[(size_t)ray * 3 + 2] = sb - 1.0f;
    }
}

// ---------------------------------------------------------------------------
extern "C" void kernel_launch(void* const* d_in, const int* in_sizes, int n_in,
                              void* d_out, int out_size, void* d_ws, size_t ws_size,
                              hipStream_t stream) {
    const float* colors    = (const float*)d_in[0];
    const float* densities = (const float*)d_in[1];
    const float* depths    = (const float*)d_in[2];

    const int n_rays = in_sizes[1] / NS;

    float* out       = (float*)d_out;
    float* out_rgb   = out;
    float* out_depth = out + (size_t)n_rays * 3;
    float* out_w     = out + (size_t)n_rays * 4;

    hipLaunchKernelGGL(raymarch_kernel,
                       dim3((n_rays + RPB - 1) / RPB), dim3(256), 0, stream,
                       colors, densities, depths,
                       out_rgb, out_depth, out_w, n_rays);
}